// Round 3
// baseline (282.148 us; speedup 1.0000x reference)
//
#include <hip/hip_runtime.h>

#define N_NODES 100000
#define D 128
#define N_EDGES 640000
#define TOT_EDGES (3 * N_EDGES)   // 1,920,000

#define NB   1024                 // buckets (node ranges)
#define NPB  98                   // nodes per bucket (1024*98 >= 100000)
#define BCAP 2304                 // record cap per bucket (mean 1875, ~+10 sigma)
#define OVF_CAP 16384
#define EPB  3072                 // edges per binA block
#define BINA_BLOCKS (TOT_EDGES / EPB)   // 625
#define EPT  (EPB / 256)                // 12 edges per thread
#define NKEY 512                  // pow2 >= NPB*4 (local*4+set sort key space)
#define CAST_BLOCKS ((N_NODES * D / 4 + 255) / 256)   // 12500

// ---------------- fast-path ws layout (bytes); total 60,562,120 ------------
// (must stay <= 60,901,440)
#define WS_OVFCNT 0
#define WS_BCUR   64                         // int, stride 16 ints (64B/bucket) x1024
#define WS_OVF    65600                      // int4[OVF_CAP], 256 KB
#define WS_TMP    327744                     // int2[NB*BCAP], 18.87 MB
#define WS_FREC   19202112                   // int2[TOT_EDGES], 15.36 MB
#define WS_OFFS   34562112                   // int[N_NODES+1]
#define WS_XB     34962120                   // ushort[N_NODES*D] bf16, 25.6 MB
#define WS_TOTAL_FAST 60562120

#ifndef __has_builtin
#define __has_builtin(x) 0
#endif
#if __has_builtin(__builtin_amdgcn_alignbit)
#define ALIGN16(hi, lo) __builtin_amdgcn_alignbit((hi), (lo), 16)
#else
#define ALIGN16(hi, lo) (((hi) << 16) | ((lo) >> 16))
#endif

__device__ __forceinline__ void load_r(const float* z0, const float* z1,
                                       const float* z2, const float* z3,
                                       float& r0, float& r1, float& r2, float& r3) {
    r0 = fmaxf(z0[0], 0.0f);
    r1 = fmaxf(z1[0], 0.0f);
    r2 = fmaxf(z2[0], 0.0f);
    r3 = fmaxf(z3[0], 0.0f);
    float inv = 1.0f / (r0 + r1 + r2 + r3 + 1e-6f);
    r0 *= inv; r1 *= inv; r2 *= inv; r3 *= inv;
}

__device__ __forceinline__ unsigned short bf16rn(float f) {
    unsigned int u = __float_as_uint(f);
    u += 0x7FFFu + ((u >> 16) & 1u);   // round to nearest even
    return (unsigned short)(u >> 16);
}

// ---------------------------------------------------------------------------
// prep: merged cast (x -> bf16 xb) + binA (LDS-aggregated edge binning into
// 1024 node-range buckets). Independent work split by blockIdx; merging
// removes a dispatch and overlaps cast's pure-BW phase with binA's atomics.
// tmp rec: x = dst(17) | set<<17 (2) | local<<19 (7), y = f32 scale.
// ---------------------------------------------------------------------------
__global__ __launch_bounds__(256) void prep_kernel(
        const float* __restrict__ x, ushort* __restrict__ xb,
        const int* __restrict__ ei1, const float* __restrict__ w1,
        const int* __restrict__ ei2, const float* __restrict__ w2,
        const int* __restrict__ ei3, const float* __restrict__ w3,
        const float* __restrict__ z0, const float* __restrict__ z1,
        const float* __restrict__ z2, const float* __restrict__ z3,
        int* __restrict__ bcur, int* __restrict__ ovf_count,
        int4* __restrict__ ovf, int2* __restrict__ tmp) {
    if (blockIdx.x >= BINA_BLOCKS) {
        // ---- cast branch ----
        int i = (blockIdx.x - BINA_BLOCKS) * 256 + threadIdx.x;
        if (i < N_NODES * D / 4) {
            float4 v = ((const float4*)x)[i];
            ushort4 h;
            h.x = bf16rn(v.x); h.y = bf16rn(v.y); h.z = bf16rn(v.z); h.w = bf16rn(v.w);
            ((ushort4*)xb)[i] = h;
        }
        return;
    }
    // ---- binA branch ----
    __shared__ int hist[NB];
    __shared__ int base[NB];
    int t = threadIdx.x;
    for (int i = t; i < NB; i += 256) hist[i] = 0;
    __syncthreads();

    float r0, r1, r2, r3;
    load_r(z0, z1, z2, z3, r0, r1, r2, r3);

    int e0 = blockIdx.x * EPB;
    int rank[EPT];
    int bkt[EPT];
    int rxv[EPT];
    float scv[EPT];

#pragma unroll
    for (int k = 0; k < EPT; ++k) {
        int e = e0 + t + k * 256;
        int set = e / N_EDGES;
        int idx = e - set * N_EDGES;
        const int* ei;  const float* w;  float rk;
        if      (set == 0) { ei = ei1; w = w1; rk = r1; }
        else if (set == 1) { ei = ei2; w = w2; rk = r2; }
        else               { ei = ei3; w = w3; rk = r3; }
        int src = ei[idx];
        int dst = ei[N_EDGES + idx];
        int b = src / NPB;
        int local = src - b * NPB;
        bkt[k]  = b;
        rxv[k]  = dst | (set << 17) | (local << 19);
        scv[k]  = rk * w[idx];
        rank[k] = atomicAdd(&hist[b], 1);
    }
    __syncthreads();

    for (int i = t; i < NB; i += 256) {
        int h = hist[i];
        base[i] = h ? atomicAdd(&bcur[i * 16], h) : 0;
    }
    __syncthreads();

#pragma unroll
    for (int k = 0; k < EPT; ++k) {
        int b = bkt[k];
        int pos = base[b] + rank[k];
        if (pos < BCAP) {
            tmp[(size_t)b * BCAP + pos] = make_int2(rxv[k], __float_as_int(scv[k]));
        } else {
            int o = atomicAdd(ovf_count, 1);
            int src = b * NPB + ((rxv[k] >> 19) & 0x7F);
            if (o < OVF_CAP) ovf[o] = make_int4(src, rxv[k] & 0x7FFFF,
                                                __float_as_int(scv[k]), 0);
        }
    }
}

// ---------------------------------------------------------------------------
// binB: per-bucket local CSR via counting sort on key = local*4 + set.
// Prologue re-derives this bucket's global base by scanning all 1024 clamped
// bucket counts in LDS (replaces the separate scanB dispatch). 1024 blocks
// -> 4 blocks/CU (vs 1 at NB=256): 4x the latency-hiding TLP.
// ---------------------------------------------------------------------------
__global__ __launch_bounds__(256) void binB_kernel(
        const int* __restrict__ bcur, const int2* __restrict__ tmp,
        int2* __restrict__ frecs, int* __restrict__ offsets) {
    __shared__ int sc4[256];
    __shared__ int d[NKEY];
    __shared__ int ts[256];
    __shared__ int cur[NKEY];
    __shared__ int sh_gbase, sh_n;
    int b = blockIdx.x;
    int t = threadIdx.x;

    d[t] = 0; d[t + 256] = 0;

    // ---- bucket-count scan (all blocks compute identical scan) ----
    int v4[4];
    int cex[4];
    int tsum = 0;
#pragma unroll
    for (int k = 0; k < 4; ++k) {
        int g = 4 * t + k;
        int v = bcur[g * 16];
        if (v > BCAP) v = BCAP;
        cex[k] = tsum;
        tsum += v;
        v4[k] = v;
    }
    sc4[t] = tsum;
    __syncthreads();
    for (int off = 1; off < 256; off <<= 1) {
        int v = (t >= off) ? sc4[t - off] : 0;
        __syncthreads();
        sc4[t] += v;
        __syncthreads();
    }
    if (t == (b >> 2)) {
        sh_gbase = sc4[t] - tsum + cex[b & 3];
        sh_n     = v4[b & 3];
    }
    if (b == NB - 1 && t == 255) offsets[N_NODES] = sc4[255];
    __syncthreads();
    int gbase = sh_gbase;
    int n     = sh_n;

    // ---- histogram over this bucket's records ----
    for (int i = t; i < n; i += 256) {
        int rx = tmp[(size_t)b * BCAP + i].x;
        int key = (((rx >> 19) & 0x7F) << 2) | ((rx >> 17) & 3);
        atomicAdd(&d[key], 1);
    }
    __syncthreads();

    // ---- key scan: thread t owns keys 2t, 2t+1 ----
    int k0 = d[2 * t], k1 = d[2 * t + 1];
    int tot = k0 + k1;
    ts[t] = tot;
    __syncthreads();
    for (int off = 1; off < 256; off <<= 1) {
        int v = (t >= off) ? ts[t - off] : 0;
        __syncthreads();
        ts[t] += v;
        __syncthreads();
    }
    int tbase = ts[t] - tot;
    cur[2 * t]     = tbase;
    cur[2 * t + 1] = tbase + k0;
    __syncthreads();

    // ---- per-node offsets (cur still holds exclusive bases) ----
    if (t < NPB) {
        int node = b * NPB + t;
        if (node < N_NODES) offsets[node] = gbase + cur[t << 2];
    }
    __syncthreads();

    // ---- emit sorted records ----
    for (int i = t; i < n; i += 256) {
        int2 rec = tmp[(size_t)b * BCAP + i];
        int key = (((rec.x >> 19) & 0x7F) << 2) | ((rec.x >> 17) & 3);
        int pos = atomicAdd(&cur[key], 1);
        frecs[gbase + pos] = make_int2(rec.x & 0x7FFFF, rec.y);
    }
}

// ---------------------------------------------------------------------------
// gatherb v4: wave per node; 8 records per iteration = two independent uint4
// row loads in flight (2x MLP vs v3). Rotation at load time via packed bf16x2
// word shift; 8 named scalar accumulators (no aggregates -> no scratch).
// ---------------------------------------------------------------------------
#define GB_ACC(V, RX, RY)                                                      \
    {                                                                          \
        int sh = ((RX) >> 17) & 3;                                             \
        float sc = __int_as_float(RY);                                         \
        unsigned int pw = (unsigned int)__shfl((int)(V).w, prevq);             \
        unsigned int s1x = ALIGN16((V).x, pw);                                 \
        unsigned int s1y = ALIGN16((V).y, (V).x);                              \
        unsigned int s1z = ALIGN16((V).z, (V).y);                              \
        unsigned int s1w = ALIGN16((V).w, (V).z);                              \
        unsigned int u0 = (sh == 0) ? (V).x : (sh == 1) ? s1x : pw;            \
        unsigned int u1 = (sh == 0) ? (V).y : (sh == 1) ? s1y : (V).x;         \
        unsigned int u2 = (sh == 0) ? (V).z : (sh == 1) ? s1z : (V).y;         \
        unsigned int u3 = (sh == 0) ? (V).w : (sh == 1) ? s1w : (V).z;         \
        acc0 += sc * __uint_as_float(u0 << 16);                                \
        acc1 += sc * __uint_as_float(u0 & 0xFFFF0000u);                        \
        acc2 += sc * __uint_as_float(u1 << 16);                                \
        acc3 += sc * __uint_as_float(u1 & 0xFFFF0000u);                        \
        acc4 += sc * __uint_as_float(u2 << 16);                                \
        acc5 += sc * __uint_as_float(u2 & 0xFFFF0000u);                        \
        acc6 += sc * __uint_as_float(u3 << 16);                                \
        acc7 += sc * __uint_as_float(u3 & 0xFFFF0000u);                        \
    }

__global__ __launch_bounds__(256) void gatherb_kernel(
        const float* __restrict__ x, const ushort* __restrict__ xb,
        const int* __restrict__ offsets, const int2* __restrict__ recs,
        const float* __restrict__ z0, const float* __restrict__ z1,
        const float* __restrict__ z2, const float* __restrict__ z3,
        float* __restrict__ out) {
    int wid  = (blockIdx.x * blockDim.x + threadIdx.x) >> 6;
    int lane = threadIdx.x & 63;
    if (wid >= N_NODES) return;

    float r0, r1, r2, r3;
    load_r(z0, z1, z2, z3, r0, r1, r2, r3);

    int qt    = lane >> 4;                    // record slot within 4-group
    int l16   = lane & 15;                    // 16 lanes x uint4 = 256 B row
    int prevq = (qt << 4) | ((l16 + 15) & 15);

    int beg = offsets[wid];
    int end = offsets[wid + 1];
    int count = end - beg;
    int cnt64 = (count < 64) ? count : 64;

    int mrx = 0, mry = 0;                     // pad: row 0, scale 0
    if (lane < cnt64) { int2 rec = recs[beg + lane]; mrx = rec.x; mry = rec.y; }

    float acc0 = 0.f, acc1 = 0.f, acc2 = 0.f, acc3 = 0.f;
    float acc4 = 0.f, acc5 = 0.f, acc6 = 0.f, acc7 = 0.f;

    for (int j = 0; j < cnt64; j += 8) {      // 2 loads in flight per iter
        int sa = j + qt;                      // <= 63 (j <= 56)
        int sb = j + 4 + qt;                  // <= 63
        int rxa = __shfl(mrx, sa), rya = __shfl(mry, sa);
        int rxb = __shfl(mrx, sb), ryb = __shfl(mry, sb);
        const uint4* pa = (const uint4*)(xb + (size_t)(rxa & 0x1FFFF) * D);
        const uint4* pb = (const uint4*)(xb + (size_t)(rxb & 0x1FFFF) * D);
        uint4 va = pa[l16];
        uint4 vb = pb[l16];
        GB_ACC(va, rxa, rya)
        GB_ACC(vb, rxb, ryb)
    }
    for (int q = 64; q < count; q += 4) {     // rare high-degree tail
        int qq = q + qt;
        int rx = 0, ry = 0;
        if (qq < count) { int2 rec = recs[beg + qq]; rx = rec.x; ry = rec.y; }
        const uint4* pp = (const uint4*)(xb + (size_t)(rx & 0x1FFFF) * D);
        uint4 vv = pp[l16];
        GB_ACC(vv, rx, ry)
    }

    // reduce partial sums across the 4 lane quarters
    acc0 += __shfl_xor(acc0, 16); acc0 += __shfl_xor(acc0, 32);
    acc1 += __shfl_xor(acc1, 16); acc1 += __shfl_xor(acc1, 32);
    acc2 += __shfl_xor(acc2, 16); acc2 += __shfl_xor(acc2, 32);
    acc3 += __shfl_xor(acc3, 16); acc3 += __shfl_xor(acc3, 32);
    acc4 += __shfl_xor(acc4, 16); acc4 += __shfl_xor(acc4, 32);
    acc5 += __shfl_xor(acc5, 16); acc5 += __shfl_xor(acc5, 32);
    acc6 += __shfl_xor(acc6, 16); acc6 += __shfl_xor(acc6, 32);
    acc7 += __shfl_xor(acc7, 16); acc7 += __shfl_xor(acc7, 32);

    if (lane < 16) {
        const float4* xr = (const float4*)(x + (size_t)wid * D);
        float4 xlo = xr[2 * l16];
        float4 xhi = xr[2 * l16 + 1];
        float4 olo, ohi;
        olo.x = r0 * xlo.x + acc0;
        olo.y = r0 * xlo.y + acc1;
        olo.z = r0 * xlo.z + acc2;
        olo.w = r0 * xlo.w + acc3;
        ohi.x = r0 * xhi.x + acc4;
        ohi.y = r0 * xhi.y + acc5;
        ohi.z = r0 * xhi.z + acc6;
        ohi.w = r0 * xhi.w + acc7;
        float4* op = (float4*)(out + (size_t)wid * D);
        op[2 * l16]     = olo;
        op[2 * l16 + 1] = ohi;
    }
}

// overflow cleanup: wave per record, atomic add (expected ~0 records)
__global__ void ovf_kernel(const float* __restrict__ x,
                           const int* __restrict__ ovf_count,
                           const int4* __restrict__ ovf,
                           float* __restrict__ out) {
    int total_waves = (gridDim.x * blockDim.x) >> 6;
    int gw   = (blockIdx.x * blockDim.x + threadIdx.x) >> 6;
    int lane = threadIdx.x & 63;
    int n = *ovf_count;
    if (n > OVF_CAP) n = OVF_CAP;
    for (int r = gw; r < n; r += total_waves) {
        int4 rec = ovf[r];
        int src = rec.x;
        int dst = rec.y & 0x1FFFF;
        int sh  = (rec.y >> 17) & 3;
        float sc = __int_as_float(rec.z);
        const float* xr = x + (size_t)dst * D;
        float* orow = out + (size_t)src * D;
        int c0 = 2 * lane, c1 = 2 * lane + 1;
        atomicAdd(&orow[c0], sc * xr[(c0 - sh) & 127]);
        atomicAdd(&orow[c1], sc * xr[(c1 - sh) & 127]);
    }
}

// ===========================================================================
// MID TIER fallback (exact-CSR path, fp32 gather), if ws too small.
// ===========================================================================
#define SCAN_BLOCKS ((N_NODES + 255) / 256)   // 391
#define WS_COUNTS   0
#define WS_OFFSETS  400000
#define WS_CURSORS  800008
#define WS_BSUM     1200008
#define WS_BPRE     1201576
#define WS_RECS     1203144
#define WS_NEEDED_MID (WS_RECS + (size_t)TOT_EDGES * 8)

__global__ void hist_kernel(const int* __restrict__ ei1, const int* __restrict__ ei2,
                            const int* __restrict__ ei3, int* __restrict__ counts) {
    int e = blockIdx.x * blockDim.x + threadIdx.x;
    if (e >= TOT_EDGES) return;
    int set = e / N_EDGES;
    int idx = e - set * N_EDGES;
    const int* ei = (set == 0) ? ei1 : (set == 1) ? ei2 : ei3;
    atomicAdd(&counts[ei[idx]], 1);
}

__global__ void scan1_kernel(const int* __restrict__ counts,
                             int* __restrict__ offsets, int* __restrict__ bsum) {
    __shared__ int s[256];
    int t = threadIdx.x;
    int i = blockIdx.x * 256 + t;
    int v = (i < N_NODES) ? counts[i] : 0;
    s[t] = v;
    __syncthreads();
    for (int off = 1; off < 256; off <<= 1) {
        int u = (t >= off) ? s[t - off] : 0;
        __syncthreads();
        s[t] += u;
        __syncthreads();
    }
    if (i < N_NODES) offsets[i] = s[t] - v;
    if (t == 255) bsum[blockIdx.x] = s[255];
}

__global__ void scan2_kernel(const int* __restrict__ bsum, int* __restrict__ bpre) {
    __shared__ int s[512];
    int t = threadIdx.x;
    int v = (t < SCAN_BLOCKS) ? bsum[t] : 0;
    s[t] = v;
    __syncthreads();
    for (int off = 1; off < 512; off <<= 1) {
        int u = (t >= off) ? s[t - off] : 0;
        __syncthreads();
        s[t] += u;
        __syncthreads();
    }
    if (t < SCAN_BLOCKS) bpre[t] = s[t] - v;
}

__global__ void scan3_kernel(int* __restrict__ offsets, const int* __restrict__ bpre,
                             int* __restrict__ cursors) {
    int i = blockIdx.x * 256 + threadIdx.x;
    if (i < N_NODES) {
        int v = offsets[i] + bpre[blockIdx.x];
        offsets[i] = v;
        cursors[i] = v;
    }
    if (i == 0) offsets[N_NODES] = TOT_EDGES;
}

__global__ void fill_kernel(const int* __restrict__ ei1, const float* __restrict__ w1,
                            const int* __restrict__ ei2, const float* __restrict__ w2,
                            const int* __restrict__ ei3, const float* __restrict__ w3,
                            const float* __restrict__ z0, const float* __restrict__ z1,
                            const float* __restrict__ z2, const float* __restrict__ z3,
                            int* __restrict__ cursors, int2* __restrict__ recs) {
    int e = blockIdx.x * blockDim.x + threadIdx.x;
    if (e >= TOT_EDGES) return;
    int set = e / N_EDGES;
    int idx = e - set * N_EDGES;
    const int* ei;  const float* w;
    if      (set == 0) { ei = ei1; w = w1; }
    else if (set == 1) { ei = ei2; w = w2; }
    else               { ei = ei3; w = w3; }
    float r0, r1, r2, r3;
    load_r(z0, z1, z2, z3, r0, r1, r2, r3);
    float rk = (set == 0) ? r1 : (set == 1) ? r2 : r3;
    int src = ei[idx];
    int dst = ei[N_EDGES + idx];
    float scale = rk * w[idx];
    int pos = atomicAdd(&cursors[src], 1);
    recs[pos] = make_int2(dst | (set << 17), __float_as_int(scale));
}

__global__ void gatherd_kernel(const float* __restrict__ x,
                               const int* __restrict__ offsets,
                               const int2* __restrict__ recs,
                               const float* __restrict__ z0, const float* __restrict__ z1,
                               const float* __restrict__ z2, const float* __restrict__ z3,
                               float* __restrict__ out) {
    int wid  = (blockIdx.x * blockDim.x + threadIdx.x) >> 6;
    int lane = threadIdx.x & 63;
    if (wid >= N_NODES) return;
    float r0, r1, r2, r3;
    load_r(z0, z1, z2, z3, r0, r1, r2, r3);
    float2 xv = ((const float2*)(x + (size_t)wid * D))[lane];
    int beg = offsets[wid];
    int end = offsets[wid + 1];
    float2 a0 = {0.f, 0.f}, a1 = {0.f, 0.f}, a2 = {0.f, 0.f};
    for (int j = beg; j < end; ++j) {
        int2 rec = recs[j];
        float2 v = ((const float2*)(x + (size_t)(rec.x & 0x1FFFF) * D))[lane];
        int sh = (rec.x >> 17) & 3;
        float sc = __int_as_float(rec.y);
        if      (sh == 0) { a0.x += sc * v.x; a0.y += sc * v.y; }
        else if (sh == 1) { a1.x += sc * v.x; a1.y += sc * v.y; }
        else               { a2.x += sc * v.x; a2.y += sc * v.y; }
    }
    int prev = (lane + 63) & 63;
    float r1y = __shfl(a1.y, prev);
    float r2x = __shfl(a2.x, prev);
    float r2y = __shfl(a2.y, prev);
    float2 o;
    o.x = r0 * xv.x + a0.x + r1y  + r2x;
    o.y = r0 * xv.y + a0.y + a1.x + r2y;
    ((float2*)(out + (size_t)wid * D))[lane] = o;
}

extern "C" void kernel_launch(void* const* d_in, const int* in_sizes, int n_in,
                              void* d_out, int out_size, void* d_ws, size_t ws_size,
                              hipStream_t stream) {
    const float* x   = (const float*)d_in[0];
    const int*   ei1 = (const int*)  d_in[1];
    const float* w1  = (const float*)d_in[2];
    const int*   ei2 = (const int*)  d_in[3];
    const float* w2  = (const float*)d_in[4];
    const int*   ei3 = (const int*)  d_in[5];
    const float* w3  = (const float*)d_in[6];
    const float* z0  = (const float*)d_in[7];
    const float* z1  = (const float*)d_in[8];
    const float* z2  = (const float*)d_in[9];
    const float* z3  = (const float*)d_in[10];
    float* out = (float*)d_out;
    char* wsc = (char*)d_ws;

    if (ws_size >= WS_TOTAL_FAST) {
        int*    ovf_count = (int*)   (wsc + WS_OVFCNT);
        int*    bcur      = (int*)   (wsc + WS_BCUR);
        int4*   ovf       = (int4*)  (wsc + WS_OVF);
        int2*   tmp       = (int2*)  (wsc + WS_TMP);
        int2*   frecs     = (int2*)  (wsc + WS_FREC);
        int*    offsets   = (int*)   (wsc + WS_OFFS);
        ushort* xb        = (ushort*)(wsc + WS_XB);

        hipMemsetAsync(wsc, 0, WS_OVF, stream);   // ovf_count + bucket cursors
        prep_kernel<<<BINA_BLOCKS + CAST_BLOCKS, 256, 0, stream>>>(
            x, xb, ei1, w1, ei2, w2, ei3, w3, z0, z1, z2, z3,
            bcur, ovf_count, ovf, tmp);
        binB_kernel<<<NB, 256, 0, stream>>>(bcur, tmp, frecs, offsets);
        gatherb_kernel<<<(N_NODES * 64 + 255) / 256, 256, 0, stream>>>(x, xb, offsets,
                                                                       frecs, z0, z1, z2, z3,
                                                                       out);
        ovf_kernel<<<128, 256, 0, stream>>>(x, ovf_count, ovf, out);
    } else {
        int*  counts  = (int*) (wsc + WS_COUNTS);
        int*  offsets = (int*) (wsc + WS_OFFSETS);
        int*  cursors = (int*) (wsc + WS_CURSORS);
        int*  bsum    = (int*) (wsc + WS_BSUM);
        int*  bpre    = (int*) (wsc + WS_BPRE);
        int2* recs    = (int2*)(wsc + WS_RECS);

        hipMemsetAsync(counts, 0, N_NODES * sizeof(int), stream);
        hist_kernel<<<TOT_EDGES / 256, 256, 0, stream>>>(ei1, ei2, ei3, counts);
        scan1_kernel<<<SCAN_BLOCKS, 256, 0, stream>>>(counts, offsets, bsum);
        scan2_kernel<<<1, 512, 0, stream>>>(bsum, bpre);
        scan3_kernel<<<SCAN_BLOCKS, 256, 0, stream>>>(offsets, bpre, cursors);
        fill_kernel<<<TOT_EDGES / 256, 256, 0, stream>>>(ei1, w1, ei2, w2, ei3, w3,
                                                         z0, z1, z2, z3, cursors, recs);
        gatherd_kernel<<<(N_NODES * 64 + 255) / 256, 256, 0, stream>>>(x, offsets, recs,
                                                                       z0, z1, z2, z3, out);
    }
}